// Round 9
// baseline (37.730 us; speedup 1.0000x reference)
//
#include <hip/hip_runtime.h>
#include <hip/hip_fp16.h>
#include <hip/hip_bf16.h>

typedef unsigned int u32;
typedef unsigned short u16;
typedef short short8 __attribute__((ext_vector_type(8)));
typedef float f32x4 __attribute__((ext_vector_type(4)));

#define IN_F 4096
#define OUT_F 11008
#define MROWS 32
#define CCOLS 2048   // packed int32s per output row
#define NGRP 32
#define KSPL 8
#define NBX (OUT_F / 64)                          // 172
#define XFRAG_BYTES ((size_t)MROWS * IN_F * 2)    // 262144
#define SZ_BYTES ((size_t)NGRP * OUT_F * 4)       // 1409024
#define SF_OFF XFRAG_BYTES
#define ZA_OFF (SF_OFF + SZ_BYTES)
#define PART_OFF (ZA_OFF + SZ_BYTES)
#define PART_BYTES ((size_t)KSPL * MROWS * OUT_F * 4)   // 11272192
#define WS_NEED (PART_OFF + PART_BYTES)

typedef const __attribute__((address_space(1))) void* gas_t;
typedef __attribute__((address_space(3))) void* las_t;
__device__ __forceinline__ void gl_lds16(const void* g, void* l) {
  __builtin_amdgcn_global_load_lds((gas_t)g, (las_t)l, 16, 0, 0);
}

__device__ __forceinline__ float bf2f(u16 b) {
  u32 t = ((u32)b) << 16;
  return __builtin_bit_cast(float, t);
}
__device__ __forceinline__ u32 f2bf_rne(float f) {
  u32 b = __builtin_bit_cast(u32, f);
  return (b + 0x7FFFu + ((b >> 16) & 1u)) >> 16;
}
__device__ __forceinline__ float h2f(u16 h) {
  return __half2float(__builtin_bit_cast(__half, h));
}

// mode: 0 = bf16 storage, 1 = f32 storage, 2 = f16 storage (wave-uniform).
__device__ __forceinline__ u32 detect_mode(const u16* sc) {
  int l = (int)(threadIdx.x & 63u);
  u16 u = sc[2 * l];
  int e = (u >> 7) & 0xFF;
  unsigned long long mA = __ballot(e >= 114 && e <= 124);  // bf16 exps of [1e-3,2.1e-2)
  unsigned long long mC = __ballot(e >= 36 && e <= 88);    // f16 bit patterns
  int cA = __popcll(mA), cC = __popcll(mC);
  return (cA >= 48) ? 0u : ((cC >= 48) ? 2u : 1u);
}

__device__ __forceinline__ float ld_sz(const void* p, int idx, u32 mode) {
  if (mode == 0) return bf2f(((const u16*)p)[idx]);
  if (mode == 2) return h2f(((const u16*)p)[idx]);
  return ((const float*)p)[idx];
}

// dequant one packed int32 (byte: high nibble = even k, low = odd k) -> 2 bf16
// magic: 0x43000000 | (n<<16) == 128 + n exactly; za = zero - 128*scale
__device__ __forceinline__ u32 deq2(u32 v, float sf, float za) {
  float uh = __builtin_bit_cast(float, 0x43000000u | ((v << 12) & 0xF0000u));
  float ul = __builtin_bit_cast(float, 0x43000000u | ((v << 16) & 0xF0000u));
  float wh = __builtin_fmaf(uh, sf, za);
  float wl = __builtin_fmaf(ul, sf, za);
  __hip_bfloat162 pk = __float22bfloat162_rn(make_float2(wh, wl));  // v_cvt_pk_bf16_f32
  u32 r;
  __builtin_memcpy(&r, &pk, 4);   // bf(wh) low 16, bf(wl) high 16
  return r;
}
__device__ __forceinline__ uint4 deq4(uint4 bv, float sf, float za) {
  uint4 r;
  r.x = deq2(bv.x, sf, za); r.y = deq2(bv.y, sf, za);
  r.z = deq2(bv.z, sf, za); r.w = deq2(bv.w, sf, za);
  return r;
}

// load 8 consecutive x elements at element-offset eoff -> packed bf16x8
__device__ __forceinline__ uint4 lda8(const void* x, int eoff, u32 mode) {
  if (mode == 0) return *reinterpret_cast<const uint4*>((const u16*)x + eoff);
  if (mode == 1) {
    float4 u = *reinterpret_cast<const float4*>((const float*)x + eoff);
    float4 v = *reinterpret_cast<const float4*>((const float*)x + eoff + 4);
    uint4 r;
    r.x = f2bf_rne(u.x) | (f2bf_rne(u.y) << 16);
    r.y = f2bf_rne(u.z) | (f2bf_rne(u.w) << 16);
    r.z = f2bf_rne(v.x) | (f2bf_rne(v.y) << 16);
    r.w = f2bf_rne(v.z) | (f2bf_rne(v.w) << 16);
    return r;
  }
  uint4 h = *reinterpret_cast<const uint4*>((const u16*)x + eoff);
  uint4 r;
  r.x = f2bf_rne(h2f((u16)(h.x & 0xFFFF))) | (f2bf_rne(h2f((u16)(h.x >> 16))) << 16);
  r.y = f2bf_rne(h2f((u16)(h.y & 0xFFFF))) | (f2bf_rne(h2f((u16)(h.y >> 16))) << 16);
  r.z = f2bf_rne(h2f((u16)(h.z & 0xFFFF))) | (f2bf_rne(h2f((u16)(h.z >> 16))) << 16);
  r.w = f2bf_rne(h2f((u16)(h.w & 0xFFFF))) | (f2bf_rne(h2f((u16)(h.w >> 16))) << 16);
  return r;
}

// Fused prep: (i) pack x into MFMA A-fragment order:
//   xfrag[((s*2+h)*64 + lane)*8] = x[h*16+(lane&15)][s*32+(lane>>4)*8 ..+8]
// (ii) transpose+precompute sfT[g][o] = scale, zaT[g][o] = zero - 128*scale.
__global__ __launch_bounds__(256) void qz_prep(
    const void* __restrict__ x, const void* __restrict__ scales,
    const void* __restrict__ zeros, u16* __restrict__ xfrag,
    float* __restrict__ sfT, float* __restrict__ zaT) {
  const u32 mode = detect_mode((const u16*)scales);
  const int t = (int)blockIdx.x * 256 + (int)threadIdx.x;  // 368640 total
  if (t < 16384) {
    const int s = t >> 7, h = (t >> 6) & 1, lane = t & 63;
    const int q = lane & 15, p = lane >> 4;
    const int src = (h * 16 + q) * IN_F + s * 32 + p * 8;
    *reinterpret_cast<uint4*>(xfrag + (size_t)t * 8) = lda8(x, src, mode);
  } else {
    const int u = t - 16384;                   // u = g*OUT_F + o (writes coalesced)
    if (u < NGRP * OUT_F) {
      const int g = u / OUT_F, o = u - g * OUT_F;
      const float sfv = ld_sz(scales, o * NGRP + g, mode);
      const float zfv = ld_sz(zeros, o * NGRP + g, mode);
      sfT[u] = sfv;
      zaT[u] = zfv - 128.0f * sfv;
    }
  }
}

// Steady-state coalesced dequant-GEMM. Block = 4 waves; wave wid owns o-rows
// o0..o0+15 (o0 = bx*64+wid*16), k-slice ksl = 16 k32-steps (two 8-step
// phases). Per step ONE wave-private gl_lds stages the 16x64B B panel
// (16 cache lines/instr); refill for phase-2 step s is issued right after
// phase-1 step s -> 8-deep pipeline, continuously full (the round-8 kernel
// was 100% prologue). Counted waits, FIFO order pinned by asm clobbers:
//   issue order: S(8 scale/za) | A(16) | B0..B7 | per-step refill groups of 3
//   phase-1 step s: need B_s (pos 24+s), issued = 32+3s -> vmcnt(7+2s)
//   phase-2 step s: need refill grp s (newest pos 34+3s), issued=56 -> vmcnt(21-3s)
// No __syncthreads anywhere: LDS is wave-private. Chunk-XOR swizzle within
// the 64B line (free globally, 2-way banks on ds_read, m136).
// MFMA 16x16x32 bf16; C/D col=lane&15, row=(lane>>4)*4+reg [m89-verified].
__global__ __launch_bounds__(256, 4) void qv_gemm(
    const u16* __restrict__ xfrag, const int* __restrict__ packed,
    const float* __restrict__ sfT, const float* __restrict__ zaT,
    float* __restrict__ part) {
  __shared__ __align__(16) char smem[4][8][1024];
  const int tid = (int)threadIdx.x;
  const int lane = tid & 63, wid = tid >> 6;
  const int q = lane & 15, p = lane >> 4;
  const int o0 = (int)blockIdx.x * 64 + wid * 16;
  const int ksl = (int)blockIdx.y;               // [0, 8)
  const int o = o0 + q;
  const int k32_0 = ksl * 16;

  // --- S: 8 coalesced scale/za loads (4 quant groups of this k-slice) ---
  const int g0 = ksl * 4;
  float sf[4], za[4];
#pragma unroll
  for (int g = 0; g < 4; ++g) {
    sf[g] = sfT[(size_t)(g0 + g) * OUT_F + o];
    za[g] = zaT[(size_t)(g0 + g) * OUT_F + o];
  }
  asm volatile("" ::: "memory");

  // --- A: 16 lane-contiguous loads (steps 0..7; internal order free) ---
  const uint4* xf = reinterpret_cast<const uint4*>(xfrag);
  uint4 a0[8], a1[8];
#pragma unroll
  for (int s = 0; s < 8; ++s) {
    a0[s] = xf[(size_t)((k32_0 + s) * 2 + 0) * 64 + lane];
    a1[s] = xf[(size_t)((k32_0 + s) * 2 + 1) * 64 + lane];
  }
  asm volatile("" ::: "memory");

  // --- B: 8 gl_lds, order-pinned individually ---
  const int br = lane >> 2, bc = lane & 3;
  const int* bsrc = packed + (size_t)(o0 + br) * CCOLS + k32_0 * 16
                    + ((bc ^ ((br >> 1) & 3)) << 2);
#pragma unroll
  for (int s = 0; s < 8; ++s) {
    gl_lds16(bsrc + s * 16, &smem[wid][s][0]);
    asm volatile("" ::: "memory");
  }

  f32x4 acc0 = {0.f, 0.f, 0.f, 0.f}, acc1 = {0.f, 0.f, 0.f, 0.f};
  const int rdoff = q * 64 + ((p ^ ((q >> 1) & 3)) << 4);

#define QCOMP(S, W, SFI)                                                      \
  {                                                                           \
    asm volatile("s_waitcnt vmcnt(" #W ")" ::: "memory");                     \
    const uint4 bv = *reinterpret_cast<const uint4*>(&smem[wid][S][rdoff]);   \
    const uint4 bw = deq4(bv, sf[SFI], za[SFI]);                              \
    acc0 = __builtin_amdgcn_mfma_f32_16x16x32_bf16(                           \
        __builtin_bit_cast(short8, a0[S]), __builtin_bit_cast(short8, bw),    \
        acc0, 0, 0, 0);                                                       \
    acc1 = __builtin_amdgcn_mfma_f32_16x16x32_bf16(                           \
        __builtin_bit_cast(short8, a1[S]), __builtin_bit_cast(short8, bw),    \
        acc1, 0, 0, 0);                                                       \
  }
  // refill group for phase-2 step S (B panel + A pair at k32_0+8+S)
#define QFILL(S)                                                              \
  {                                                                           \
    gl_lds16(bsrc + (8 + S) * 16, &smem[wid][S][0]);                          \
    a0[S] = xf[(size_t)((k32_0 + 8 + S) * 2 + 0) * 64 + lane];                \
    a1[S] = xf[(size_t)((k32_0 + 8 + S) * 2 + 1) * 64 + lane];                \
  }

  QCOMP(0, 7, 0)  QFILL(0)
  QCOMP(1, 9, 0)  QFILL(1)
  QCOMP(2, 11, 0) QFILL(2)
  QCOMP(3, 13, 0) QFILL(3)
  QCOMP(4, 15, 1) QFILL(4)
  QCOMP(5, 17, 1) QFILL(5)
  QCOMP(6, 19, 1) QFILL(6)
  QCOMP(7, 21, 1) QFILL(7)

  QCOMP(0, 21, 2)
  QCOMP(1, 18, 2)
  QCOMP(2, 15, 2)
  QCOMP(3, 12, 2)
  QCOMP(4, 9, 3)
  QCOMP(5, 6, 3)
  QCOMP(6, 3, 3)
  QCOMP(7, 0, 3)
#undef QCOMP
#undef QFILL

  // lane-contiguous partial store: one 2 KB block per wave
  float* base = part + ((size_t)(ksl * NBX + (int)blockIdx.x) * 4 + wid) * 512
                + lane * 8;
  *reinterpret_cast<f32x4*>(base) = acc0;
  *reinterpret_cast<f32x4*>(base + 4) = acc1;
}

// Reduce over KSPL slices. Thread t <-> (bx, wid, lane) partial slot; each
// thread owns 8 outputs (rows p*4+rr and 16+p*4+rr of column o). Reads fully
// coalesced (32 B/thread/slice); adds bias; writes output dtype.
__global__ __launch_bounds__(256) void qr_reduce(
    const float* __restrict__ part, const void* __restrict__ scales,
    const void* __restrict__ bias, void* __restrict__ out) {
  const u32 mode = detect_mode((const u16*)scales);
  const int bx = (int)blockIdx.x;           // [0, NBX)
  const int wid = (int)threadIdx.x >> 6, lane = (int)threadIdx.x & 63;
  const int q = lane & 15, p = lane >> 4;
  const int o = bx * 64 + wid * 16 + q;

  float s0[4] = {0.f, 0.f, 0.f, 0.f}, s1[4] = {0.f, 0.f, 0.f, 0.f};
#pragma unroll
  for (int ksl = 0; ksl < KSPL; ++ksl) {
    const float* base = part + ((size_t)(ksl * NBX + bx) * 4 + wid) * 512 + lane * 8;
    const float4 v0 = *reinterpret_cast<const float4*>(base);
    const float4 v1 = *reinterpret_cast<const float4*>(base + 4);
    s0[0] += v0.x; s0[1] += v0.y; s0[2] += v0.z; s0[3] += v0.w;
    s1[0] += v1.x; s1[1] += v1.y; s1[2] += v1.z; s1[3] += v1.w;
  }
  const float bb = ld_sz(bias, o, mode);
#pragma unroll
  for (int rr = 0; rr < 4; ++rr) {
    const float v0 = s0[rr] + bb, v1 = s1[rr] + bb;
    const size_t i0 = (size_t)(p * 4 + rr) * OUT_F + o;
    const size_t i1 = (size_t)(16 + p * 4 + rr) * OUT_F + o;
    if (mode == 1) {
      ((float*)out)[i0] = v0; ((float*)out)[i1] = v1;
    } else {
      ((u16*)out)[i0] = (u16)f2bf_rne(v0);
      ((u16*)out)[i1] = (u16)f2bf_rne(v1);
    }
  }
}

// fallback for tiny ws: round-7 direct kernel (proven correct, slow)
__global__ __launch_bounds__(256, 4) void qp_direct(
    const void* __restrict__ xsrc, const int* __restrict__ packed,
    const void* __restrict__ scales, const void* __restrict__ zeros,
    const void* __restrict__ bias, void* __restrict__ out) {
  constexpr int NSTEP = 128;
  constexpr int BD = 8, AD = 4;
  const u32 mode = detect_mode((const u16*)scales);
  const int tid = (int)threadIdx.x;
  const int lane = tid & 63, wid = tid >> 6;
  const int q = lane & 15, p = lane >> 4;
  const int tile = (int)blockIdx.x * 4 + wid;
  const int o = tile * 16 + q;
  const int* pr = packed + (size_t)o * CCOLS + p * 4;
  const int ae0 = q * IN_F + p * 8;
  const int ae1 = ae0 + 16 * IN_F;
  uint4 bb[BD], a0[AD], a1[AD];
#pragma unroll
  for (int i = 0; i < BD; ++i) bb[i] = *reinterpret_cast<const uint4*>(pr + i * 16);
#pragma unroll
  for (int i = 0; i < AD; ++i) {
    a0[i] = lda8(xsrc, ae0 + i * 32, mode);
    a1[i] = lda8(xsrc, ae1 + i * 32, mode);
  }
  f32x4 acc0 = {0.f, 0.f, 0.f, 0.f}, acc1 = {0.f, 0.f, 0.f, 0.f};
  for (int g = 0; g < NSTEP / 4; ++g) {
    const float sf = ld_sz(scales, o * NGRP + g, mode);
    const float za = ld_sz(zeros, o * NGRP + g, mode) - 128.0f * sf;
#pragma unroll
    for (int u = 0; u < 4; ++u) {
      const int s = g * 4 + u;
      const uint4 bw = deq4(bb[s % BD], sf, za);
      const uint4 av0 = a0[s % AD], av1 = a1[s % AD];
      if (s + BD < NSTEP) bb[s % BD] = *reinterpret_cast<const uint4*>(pr + (s + BD) * 16);
      if (s + AD < NSTEP) {
        a0[s % AD] = lda8(xsrc, ae0 + (s + AD) * 32, mode);
        a1[s % AD] = lda8(xsrc, ae1 + (s + AD) * 32, mode);
      }
      acc0 = __builtin_amdgcn_mfma_f32_16x16x32_bf16(
          __builtin_bit_cast(short8, av0), __builtin_bit_cast(short8, bw), acc0, 0, 0, 0);
      acc1 = __builtin_amdgcn_mfma_f32_16x16x32_bf16(
          __builtin_bit_cast(short8, av1), __builtin_bit_cast(short8, bw), acc1, 0, 0, 0);
    }
  }
  const float bbv = ld_sz(bias, o, mode);
#pragma unroll
  for (int r = 0; r < 4; ++r) {
    const float v0 = acc0[r] + bbv, v1 = acc1[r] + bbv;
    const size_t i0 = (size_t)(p * 4 + r) * OUT_F + o;
    const size_t i1 = (size_t)(16 + p * 4 + r) * OUT_F + o;
    if (mode == 1) { ((float*)out)[i0] = v0; ((float*)out)[i1] = v1; }
    else { ((u16*)out)[i0] = (u16)f2bf_rne(v0); ((u16*)out)[i1] = (u16)f2bf_rne(v1); }
  }
}

extern "C" void kernel_launch(void* const* d_in, const int* in_sizes, int n_in,
                              void* d_out, int out_size, void* d_ws, size_t ws_size,
                              hipStream_t stream) {
  (void)in_sizes; (void)n_in; (void)out_size;
  const void* x      = d_in[0];
  const int* packed  = (const int*)d_in[1];
  const void* scales = d_in[2];
  const void* zeros  = d_in[3];
  const void* bias   = d_in[4];

  if (ws_size >= WS_NEED) {
    u16* xfrag = (u16*)d_ws;
    float* sfT = (float*)((char*)d_ws + SF_OFF);
    float* zaT = (float*)((char*)d_ws + ZA_OFF);
    float* part = (float*)((char*)d_ws + PART_OFF);
    qz_prep<<<1440, 256, 0, stream>>>(x, scales, zeros, xfrag, sfT, zaT);
    qv_gemm<<<dim3(NBX, KSPL), 256, 0, stream>>>(xfrag, packed, sfT, zaT, part);
    qr_reduce<<<NBX, 256, 0, stream>>>(part, scales, bias, d_out);
  } else {
    qp_direct<<<OUT_F / 64, 256, 0, stream>>>(x, packed, scales, zeros, bias, d_out);
  }
}

// Round 10
// 34.081 us; speedup vs baseline: 1.1071x; 1.1071x over previous
//
#include <hip/hip_runtime.h>
#include <hip/hip_fp16.h>
#include <hip/hip_bf16.h>

typedef unsigned int u32;
typedef unsigned short u16;
typedef short short8 __attribute__((ext_vector_type(8)));
typedef float f32x4 __attribute__((ext_vector_type(4)));

#define IN_F 4096
#define OUT_F 11008
#define MROWS 32
#define CCOLS 2048   // packed int32s per output row
#define NGRP 32
#define KSPL 8
#define NBX (OUT_F / 64)                          // 172
#define XFRAG_BYTES ((size_t)MROWS * IN_F * 2)    // 262144
#define SZ_BYTES ((size_t)NGRP * OUT_F * 4)       // 1409024
#define SF_OFF XFRAG_BYTES
#define ZA_OFF (SF_OFF + SZ_BYTES)
#define PART_OFF (ZA_OFF + SZ_BYTES)
#define PART_BYTES ((size_t)KSPL * MROWS * OUT_F * 4)   // 11272192
#define WS_NEED (PART_OFF + PART_BYTES)

typedef const __attribute__((address_space(1))) void* gas_t;
typedef __attribute__((address_space(3))) void* las_t;
__device__ __forceinline__ void gl_lds16(const void* g, void* l) {
  __builtin_amdgcn_global_load_lds((gas_t)g, (las_t)l, 16, 0, 0);
}

__device__ __forceinline__ float bf2f(u16 b) {
  u32 t = ((u32)b) << 16;
  return __builtin_bit_cast(float, t);
}
__device__ __forceinline__ u32 f2bf_rne(float f) {
  u32 b = __builtin_bit_cast(u32, f);
  return (b + 0x7FFFu + ((b >> 16) & 1u)) >> 16;
}
__device__ __forceinline__ float h2f(u16 h) {
  return __half2float(__builtin_bit_cast(__half, h));
}

// mode: 0 = bf16 storage, 1 = f32 storage, 2 = f16 storage (wave-uniform).
__device__ __forceinline__ u32 detect_mode(const u16* sc) {
  int l = (int)(threadIdx.x & 63u);
  u16 u = sc[2 * l];
  int e = (u >> 7) & 0xFF;
  unsigned long long mA = __ballot(e >= 114 && e <= 124);  // bf16 exps of [1e-3,2.1e-2)
  unsigned long long mC = __ballot(e >= 36 && e <= 88);    // f16 bit patterns
  int cA = __popcll(mA), cC = __popcll(mC);
  return (cA >= 48) ? 0u : ((cC >= 48) ? 2u : 1u);
}

__device__ __forceinline__ float ld_sz(const void* p, int idx, u32 mode) {
  if (mode == 0) return bf2f(((const u16*)p)[idx]);
  if (mode == 2) return h2f(((const u16*)p)[idx]);
  return ((const float*)p)[idx];
}

// dequant one packed int32 (byte: high nibble = even k, low = odd k) -> 2 bf16
// magic: 0x43000000 | (n<<16) == 128 + n exactly; za = zero - 128*scale
__device__ __forceinline__ u32 deq2(u32 v, float sf, float za) {
  float uh = __builtin_bit_cast(float, 0x43000000u | ((v << 12) & 0xF0000u));
  float ul = __builtin_bit_cast(float, 0x43000000u | ((v << 16) & 0xF0000u));
  float wh = __builtin_fmaf(uh, sf, za);
  float wl = __builtin_fmaf(ul, sf, za);
  __hip_bfloat162 pk = __float22bfloat162_rn(make_float2(wh, wl));  // v_cvt_pk_bf16_f32
  u32 r;
  __builtin_memcpy(&r, &pk, 4);   // bf(wh) low 16, bf(wl) high 16
  return r;
}
__device__ __forceinline__ uint4 deq4(uint4 bv, float sf, float za) {
  uint4 r;
  r.x = deq2(bv.x, sf, za); r.y = deq2(bv.y, sf, za);
  r.z = deq2(bv.z, sf, za); r.w = deq2(bv.w, sf, za);
  return r;
}

// load 8 consecutive x elements at element-offset eoff -> packed bf16x8
__device__ __forceinline__ uint4 lda8(const void* x, int eoff, u32 mode) {
  if (mode == 0) return *reinterpret_cast<const uint4*>((const u16*)x + eoff);
  if (mode == 1) {
    float4 u = *reinterpret_cast<const float4*>((const float*)x + eoff);
    float4 v = *reinterpret_cast<const float4*>((const float*)x + eoff + 4);
    uint4 r;
    r.x = f2bf_rne(u.x) | (f2bf_rne(u.y) << 16);
    r.y = f2bf_rne(u.z) | (f2bf_rne(u.w) << 16);
    r.z = f2bf_rne(v.x) | (f2bf_rne(v.y) << 16);
    r.w = f2bf_rne(v.z) | (f2bf_rne(v.w) << 16);
    return r;
  }
  uint4 h = *reinterpret_cast<const uint4*>((const u16*)x + eoff);
  uint4 r;
  r.x = f2bf_rne(h2f((u16)(h.x & 0xFFFF))) | (f2bf_rne(h2f((u16)(h.x >> 16))) << 16);
  r.y = f2bf_rne(h2f((u16)(h.y & 0xFFFF))) | (f2bf_rne(h2f((u16)(h.y >> 16))) << 16);
  r.z = f2bf_rne(h2f((u16)(h.z & 0xFFFF))) | (f2bf_rne(h2f((u16)(h.z >> 16))) << 16);
  r.w = f2bf_rne(h2f((u16)(h.w & 0xFFFF))) | (f2bf_rne(h2f((u16)(h.w >> 16))) << 16);
  return r;
}

// Fused prep: (i) pack x into MFMA A-fragment order:
//   xfrag[((s*2+h)*64 + lane)*8] = x[h*16+(lane&15)][s*32+(lane>>4)*8 ..+8]
// (ii) transpose+precompute sfT[g][o] = scale, zaT[g][o] = zero - 128*scale.
__global__ __launch_bounds__(256) void qz_prep(
    const void* __restrict__ x, const void* __restrict__ scales,
    const void* __restrict__ zeros, u16* __restrict__ xfrag,
    float* __restrict__ sfT, float* __restrict__ zaT) {
  const u32 mode = detect_mode((const u16*)scales);
  const int t = (int)blockIdx.x * 256 + (int)threadIdx.x;  // 368640 total
  if (t < 16384) {
    const int s = t >> 7, h = (t >> 6) & 1, lane = t & 63;
    const int q = lane & 15, p = lane >> 4;
    const int src = (h * 16 + q) * IN_F + s * 32 + p * 8;
    *reinterpret_cast<uint4*>(xfrag + (size_t)t * 8) = lda8(x, src, mode);
  } else {
    const int u = t - 16384;                   // u = g*OUT_F + o (writes coalesced)
    if (u < NGRP * OUT_F) {
      const int g = u / OUT_F, o = u - g * OUT_F;
      const float sfv = ld_sz(scales, o * NGRP + g, mode);
      const float zfv = ld_sz(zeros, o * NGRP + g, mode);
      sfT[u] = sfv;
      zaT[u] = zfv - 128.0f * sfv;
    }
  }
}

// Shared-A LDS dequant-GEMM (round-10 line-count fix).
// Round-9 lesson: steady-state pipelining was NEUTRAL vs pure-prologue (r8)
// -> latency already TLP-hidden; bound by VMEM LINE-REQUEST throughput
// (~17.5K lines/CU, dominated by per-wave A re-reads = 11K lines/CU).
// Fix: A-fragments for the block's 512-k slice staged ONCE per block (32 KB)
// via cooperative gl_lds; hot loop reads A with conflict-free ds_read_b128
// (zero VMEM). B stays wave-private, 4-deep counted-vmcnt pipeline.
// Prologue sync: per-wave "s_waitcnt vmcnt(4)" (A-stage done, 4 B-panels
// still in flight) + raw s_barrier -- NOT __syncthreads (would drain vmcnt 0).
// vmcnt ledger (per wave, after barrier): outstanding = B0..B3.
//   step s waits W = (s<=12 ? 3 : 15-s); refill B_{s+4} after step s (s<12).
// MFMA 16x16x32 bf16; C/D col=lane&15, row=(lane>>4)*4+reg [m89-verified].
__global__ __launch_bounds__(256, 3) void qv_gemm(
    const u16* __restrict__ xfrag, const int* __restrict__ packed,
    const float* __restrict__ sfT, const float* __restrict__ zaT,
    float* __restrict__ part) {
  __shared__ __align__(16) char smemA[32768];        // [s_loc*2+h][1024]
  __shared__ __align__(16) char smemB[4][4][1024];   // [wave][slot][panel]
  const int tid = (int)threadIdx.x;
  const int lane = tid & 63, wid = tid >> 6;
  const int q = lane & 15, p = lane >> 4;
  const int o0 = (int)blockIdx.x * 64 + wid * 16;
  const int ksl = (int)blockIdx.y;               // [0, 8)
  const int o = o0 + q;
  const int k32_0 = ksl * 16;

  // --- S: 8 coalesced scale/za loads (oldest in VMEM FIFO) ---
  const int g0 = ksl * 4;
  float sf[4], za[4];
#pragma unroll
  for (int g = 0; g < 4; ++g) {
    sf[g] = sfT[(size_t)(g0 + g) * OUT_F + o];
    za[g] = zaT[(size_t)(g0 + g) * OUT_F + o];
  }
  asm volatile("" ::: "memory");

  // --- A-stage: 8 gl_lds/wave; wave w covers s_loc = w*4 .. w*4+3 ---
#pragma unroll
  for (int j = 0; j < 4; ++j) {
#pragma unroll
    for (int h = 0; h < 2; ++h) {
      const int s_loc = wid * 4 + j;
      const int sg = k32_0 + s_loc;
      gl_lds16(xfrag + ((size_t)(sg * 2 + h) * 64 + lane) * 8,
               &smemA[(s_loc * 2 + h) * 1024]);
    }
  }
  asm volatile("" ::: "memory");

  // --- B prologue: 4 wave-private gl_lds ---
  const int br = lane >> 2, bc = lane & 3;
  const int* bsrc = packed + (size_t)(o0 + br) * CCOLS + k32_0 * 16
                    + ((bc ^ ((br >> 1) & 3)) << 2);
#pragma unroll
  for (int s = 0; s < 4; ++s) {
    gl_lds16(bsrc + s * 16, &smemB[wid][s][0]);
    asm volatile("" ::: "memory");
  }

  // prologue sync: own A-stage done (only 4 B outstanding), then barrier
  asm volatile("s_waitcnt vmcnt(4)" ::: "memory");
  __builtin_amdgcn_s_barrier();
  __builtin_amdgcn_sched_barrier(0);

  f32x4 acc0 = {0.f, 0.f, 0.f, 0.f}, acc1 = {0.f, 0.f, 0.f, 0.f};
  const int rdoff = q * 64 + ((p ^ ((q >> 1) & 3)) << 4);

#define QC(S, W, SFI)                                                         \
  {                                                                           \
    asm volatile("s_waitcnt vmcnt(" #W ")" ::: "memory");                     \
    const uint4 bv =                                                          \
        *reinterpret_cast<const uint4*>(&smemB[wid][(S) & 3][rdoff]);         \
    const uint4 av0 =                                                         \
        *reinterpret_cast<const uint4*>(&smemA[(S)*2048 + lane * 16]);        \
    const uint4 av1 =                                                         \
        *reinterpret_cast<const uint4*>(&smemA[(S)*2048 + 1024 + lane * 16]); \
    const uint4 bw = deq4(bv, sf[SFI], za[SFI]);                              \
    acc0 = __builtin_amdgcn_mfma_f32_16x16x32_bf16(                           \
        __builtin_bit_cast(short8, av0), __builtin_bit_cast(short8, bw),      \
        acc0, 0, 0, 0);                                                       \
    acc1 = __builtin_amdgcn_mfma_f32_16x16x32_bf16(                           \
        __builtin_bit_cast(short8, av1), __builtin_bit_cast(short8, bw),      \
        acc1, 0, 0, 0);                                                       \
    asm volatile("" ::: "memory");                                            \
  }
#define QF(T)                                                                 \
  {                                                                           \
    gl_lds16(bsrc + (T)*16, &smemB[wid][(T) & 3][0]);                         \
    asm volatile("" ::: "memory");                                            \
  }

  QC(0, 3, 0)  QF(4)   QC(1, 3, 0)  QF(5)
  QC(2, 3, 0)  QF(6)   QC(3, 3, 0)  QF(7)
  QC(4, 3, 1)  QF(8)   QC(5, 3, 1)  QF(9)
  QC(6, 3, 1)  QF(10)  QC(7, 3, 1)  QF(11)
  QC(8, 3, 2)  QF(12)  QC(9, 3, 2)  QF(13)
  QC(10, 3, 2) QF(14)  QC(11, 3, 2) QF(15)
  QC(12, 3, 3) QC(13, 2, 3) QC(14, 1, 3) QC(15, 0, 3)
#undef QC
#undef QF

  // lane-contiguous partial store: one 2 KB block per wave
  float* base = part + ((size_t)(ksl * NBX + (int)blockIdx.x) * 4 + wid) * 512
                + lane * 8;
  *reinterpret_cast<f32x4*>(base) = acc0;
  *reinterpret_cast<f32x4*>(base + 4) = acc1;
}

// Reduce over KSPL slices (same partial layout as qv_gemm stores).
__global__ __launch_bounds__(256) void qr_reduce(
    const float* __restrict__ part, const void* __restrict__ scales,
    const void* __restrict__ bias, void* __restrict__ out) {
  const u32 mode = detect_mode((const u16*)scales);
  const int bx = (int)blockIdx.x;           // [0, NBX)
  const int wid = (int)threadIdx.x >> 6, lane = (int)threadIdx.x & 63;
  const int q = lane & 15, p = lane >> 4;
  const int o = bx * 64 + wid * 16 + q;

  float s0[4] = {0.f, 0.f, 0.f, 0.f}, s1[4] = {0.f, 0.f, 0.f, 0.f};
#pragma unroll
  for (int ksl = 0; ksl < KSPL; ++ksl) {
    const float* base = part + ((size_t)(ksl * NBX + bx) * 4 + wid) * 512 + lane * 8;
    const float4 v0 = *reinterpret_cast<const float4*>(base);
    const float4 v1 = *reinterpret_cast<const float4*>(base + 4);
    s0[0] += v0.x; s0[1] += v0.y; s0[2] += v0.z; s0[3] += v0.w;
    s1[0] += v1.x; s1[1] += v1.y; s1[2] += v1.z; s1[3] += v1.w;
  }
  const float bb = ld_sz(bias, o, mode);
#pragma unroll
  for (int rr = 0; rr < 4; ++rr) {
    const float v0 = s0[rr] + bb, v1 = s1[rr] + bb;
    const size_t i0 = (size_t)(p * 4 + rr) * OUT_F + o;
    const size_t i1 = (size_t)(16 + p * 4 + rr) * OUT_F + o;
    if (mode == 1) {
      ((float*)out)[i0] = v0; ((float*)out)[i1] = v1;
    } else {
      ((u16*)out)[i0] = (u16)f2bf_rne(v0);
      ((u16*)out)[i1] = (u16)f2bf_rne(v1);
    }
  }
}

// fallback for tiny ws: round-7 direct kernel (proven correct, slow)
__global__ __launch_bounds__(256, 4) void qp_direct(
    const void* __restrict__ xsrc, const int* __restrict__ packed,
    const void* __restrict__ scales, const void* __restrict__ zeros,
    const void* __restrict__ bias, void* __restrict__ out) {
  constexpr int NSTEP = 128;
  constexpr int BD = 8, AD = 4;
  const u32 mode = detect_mode((const u16*)scales);
  const int tid = (int)threadIdx.x;
  const int lane = tid & 63, wid = tid >> 6;
  const int q = lane & 15, p = lane >> 4;
  const int tile = (int)blockIdx.x * 4 + wid;
  const int o = tile * 16 + q;
  const int* pr = packed + (size_t)o * CCOLS + p * 4;
  const int ae0 = q * IN_F + p * 8;
  const int ae1 = ae0 + 16 * IN_F;
  uint4 bb[BD], a0[AD], a1[AD];
#pragma unroll
  for (int i = 0; i < BD; ++i) bb[i] = *reinterpret_cast<const uint4*>(pr + i * 16);
#pragma unroll
  for (int i = 0; i < AD; ++i) {
    a0[i] = lda8(xsrc, ae0 + i * 32, mode);
    a1[i] = lda8(xsrc, ae1 + i * 32, mode);
  }
  f32x4 acc0 = {0.f, 0.f, 0.f, 0.f}, acc1 = {0.f, 0.f, 0.f, 0.f};
  for (int g = 0; g < NSTEP / 4; ++g) {
    const float sf = ld_sz(scales, o * NGRP + g, mode);
    const float za = ld_sz(zeros, o * NGRP + g, mode) - 128.0f * sf;
#pragma unroll
    for (int u = 0; u < 4; ++u) {
      const int s = g * 4 + u;
      const uint4 bw = deq4(bb[s % BD], sf, za);
      const uint4 av0 = a0[s % AD], av1 = a1[s % AD];
      if (s + BD < NSTEP) bb[s % BD] = *reinterpret_cast<const uint4*>(pr + (s + BD) * 16);
      if (s + AD < NSTEP) {
        a0[s % AD] = lda8(xsrc, ae0 + (s + AD) * 32, mode);
        a1[s % AD] = lda8(xsrc, ae1 + (s + AD) * 32, mode);
      }
      acc0 = __builtin_amdgcn_mfma_f32_16x16x32_bf16(
          __builtin_bit_cast(short8, av0), __builtin_bit_cast(short8, bw), acc0, 0, 0, 0);
      acc1 = __builtin_amdgcn_mfma_f32_16x16x32_bf16(
          __builtin_bit_cast(short8, av1), __builtin_bit_cast(short8, bw), acc1, 0, 0, 0);
    }
  }
  const float bbv = ld_sz(bias, o, mode);
#pragma unroll
  for (int r = 0; r < 4; ++r) {
    const float v0 = acc0[r] + bbv, v1 = acc1[r] + bbv;
    const size_t i0 = (size_t)(p * 4 + r) * OUT_F + o;
    const size_t i1 = (size_t)(16 + p * 4 + r) * OUT_F + o;
    if (mode == 1) { ((float*)out)[i0] = v0; ((float*)out)[i1] = v1; }
    else { ((u16*)out)[i0] = (u16)f2bf_rne(v0); ((u16*)out)[i1] = (u16)f2bf_rne(v1); }
  }
}

extern "C" void kernel_launch(void* const* d_in, const int* in_sizes, int n_in,
                              void* d_out, int out_size, void* d_ws, size_t ws_size,
                              hipStream_t stream) {
  (void)in_sizes; (void)n_in; (void)out_size;
  const void* x      = d_in[0];
  const int* packed  = (const int*)d_in[1];
  const void* scales = d_in[2];
  const void* zeros  = d_in[3];
  const void* bias   = d_in[4];

  if (ws_size >= WS_NEED) {
    u16* xfrag = (u16*)d_ws;
    float* sfT = (float*)((char*)d_ws + SF_OFF);
    float* zaT = (float*)((char*)d_ws + ZA_OFF);
    float* part = (float*)((char*)d_ws + PART_OFF);
    qz_prep<<<1440, 256, 0, stream>>>(x, scales, zeros, xfrag, sfT, zaT);
    qv_gemm<<<dim3(NBX, KSPL), 256, 0, stream>>>(xfrag, packed, sfT, zaT, part);
    qr_reduce<<<NBX, 256, 0, stream>>>(part, scales, bias, d_out);
  } else {
    qp_direct<<<OUT_F / 64, 256, 0, stream>>>(x, packed, scales, zeros, bias, d_out);
  }
}

// Round 11
// 33.345 us; speedup vs baseline: 1.1315x; 1.0221x over previous
//
#include <hip/hip_runtime.h>
#include <hip/hip_fp16.h>
#include <hip/hip_bf16.h>

typedef unsigned int u32;
typedef unsigned short u16;
typedef short short8 __attribute__((ext_vector_type(8)));
typedef float f32x4 __attribute__((ext_vector_type(4)));
typedef unsigned int u32x4 __attribute__((ext_vector_type(4)));

#define IN_F 4096
#define OUT_F 11008
#define MROWS 32
#define CCOLS 2048   // packed int32s per output row
#define NGRP 32
#define KSPL 8
#define NBX (OUT_F / 64)                          // 172
#define XFRAG_BYTES ((size_t)MROWS * IN_F * 2)    // 262144
#define SZ2_BYTES ((size_t)NGRP * OUT_F * 8)      // 2818048 (float2 table)
#define SZ_OFF XFRAG_BYTES
#define PART_OFF (SZ_OFF + SZ2_BYTES)
#define PART_BYTES ((size_t)KSPL * MROWS * OUT_F * 4)   // 11272192
#define WS_NEED (PART_OFF + PART_BYTES)

typedef const __attribute__((address_space(1))) void* gas_t;
typedef __attribute__((address_space(3))) void* las_t;
__device__ __forceinline__ void gl_lds16(const void* g, void* l) {
  __builtin_amdgcn_global_load_lds((gas_t)g, (las_t)l, 16, 0, 0);
}
// LDS byte offset of a __shared__ pointer (AS(3) ptrtoint = ds offset)
__device__ __forceinline__ u32 lds_u32(const void* p) {
  return (u32)(uintptr_t)(las_t)p;
}

__device__ __forceinline__ float bf2f(u16 b) {
  u32 t = ((u32)b) << 16;
  return __builtin_bit_cast(float, t);
}
__device__ __forceinline__ u32 f2bf_rne(float f) {
  u32 b = __builtin_bit_cast(u32, f);
  return (b + 0x7FFFu + ((b >> 16) & 1u)) >> 16;
}
__device__ __forceinline__ float h2f(u16 h) {
  return __half2float(__builtin_bit_cast(__half, h));
}

// mode: 0 = bf16 storage, 1 = f32 storage, 2 = f16 storage (wave-uniform).
__device__ __forceinline__ u32 detect_mode(const u16* sc) {
  int l = (int)(threadIdx.x & 63u);
  u16 u = sc[2 * l];
  int e = (u >> 7) & 0xFF;
  unsigned long long mA = __ballot(e >= 114 && e <= 124);  // bf16 exps of [1e-3,2.1e-2)
  unsigned long long mC = __ballot(e >= 36 && e <= 88);    // f16 bit patterns
  int cA = __popcll(mA), cC = __popcll(mC);
  return (cA >= 48) ? 0u : ((cC >= 48) ? 2u : 1u);
}

__device__ __forceinline__ float ld_sz(const void* p, int idx, u32 mode) {
  if (mode == 0) return bf2f(((const u16*)p)[idx]);
  if (mode == 2) return h2f(((const u16*)p)[idx]);
  return ((const float*)p)[idx];
}

// dequant one packed int32 (byte: high nibble = even k, low = odd k) -> 2 bf16
// magic: 0x43000000 | (n<<16) == 128 + n exactly; za = zero - 128*scale
__device__ __forceinline__ u32 deq2(u32 v, float sf, float za) {
  float uh = __builtin_bit_cast(float, 0x43000000u | ((v << 12) & 0xF0000u));
  float ul = __builtin_bit_cast(float, 0x43000000u | ((v << 16) & 0xF0000u));
  float wh = __builtin_fmaf(uh, sf, za);
  float wl = __builtin_fmaf(ul, sf, za);
  __hip_bfloat162 pk = __float22bfloat162_rn(make_float2(wh, wl));  // v_cvt_pk_bf16_f32
  u32 r;
  __builtin_memcpy(&r, &pk, 4);   // bf(wh) low 16, bf(wl) high 16
  return r;
}
__device__ __forceinline__ u32x4 deq4v(u32x4 bv, float sf, float za) {
  u32x4 r;
  r[0] = deq2(bv[0], sf, za); r[1] = deq2(bv[1], sf, za);
  r[2] = deq2(bv[2], sf, za); r[3] = deq2(bv[3], sf, za);
  return r;
}
__device__ __forceinline__ uint4 deq4(uint4 bv, float sf, float za) {
  uint4 r;
  r.x = deq2(bv.x, sf, za); r.y = deq2(bv.y, sf, za);
  r.z = deq2(bv.z, sf, za); r.w = deq2(bv.w, sf, za);
  return r;
}

// load 8 consecutive x elements at element-offset eoff -> packed bf16x8
__device__ __forceinline__ uint4 lda8(const void* x, int eoff, u32 mode) {
  if (mode == 0) return *reinterpret_cast<const uint4*>((const u16*)x + eoff);
  if (mode == 1) {
    float4 u = *reinterpret_cast<const float4*>((const float*)x + eoff);
    float4 v = *reinterpret_cast<const float4*>((const float*)x + eoff + 4);
    uint4 r;
    r.x = f2bf_rne(u.x) | (f2bf_rne(u.y) << 16);
    r.y = f2bf_rne(u.z) | (f2bf_rne(u.w) << 16);
    r.z = f2bf_rne(v.x) | (f2bf_rne(v.y) << 16);
    r.w = f2bf_rne(v.z) | (f2bf_rne(v.w) << 16);
    return r;
  }
  uint4 h = *reinterpret_cast<const uint4*>((const u16*)x + eoff);
  uint4 r;
  r.x = f2bf_rne(h2f((u16)(h.x & 0xFFFF))) | (f2bf_rne(h2f((u16)(h.x >> 16))) << 16);
  r.y = f2bf_rne(h2f((u16)(h.y & 0xFFFF))) | (f2bf_rne(h2f((u16)(h.y >> 16))) << 16);
  r.z = f2bf_rne(h2f((u16)(h.z & 0xFFFF))) | (f2bf_rne(h2f((u16)(h.z >> 16))) << 16);
  r.w = f2bf_rne(h2f((u16)(h.w & 0xFFFF))) | (f2bf_rne(h2f((u16)(h.w >> 16))) << 16);
  return r;
}

// Fused prep: (i) pack x into MFMA A-fragment order:
//   xfrag[((s*2+h)*64 + lane)*8] = x[h*16+(lane&15)][s*32+(lane>>4)*8 ..+8]
// (ii) transpose+precompute szT[g*OUT_F+o] = {scale, zero - 128*scale}.
__global__ __launch_bounds__(256) void qz_prep(
    const void* __restrict__ x, const void* __restrict__ scales,
    const void* __restrict__ zeros, u16* __restrict__ xfrag,
    float2* __restrict__ szT) {
  const u32 mode = detect_mode((const u16*)scales);
  const int t = (int)blockIdx.x * 256 + (int)threadIdx.x;  // 368640 total
  if (t < 16384) {
    const int s = t >> 7, h = (t >> 6) & 1, lane = t & 63;
    const int q = lane & 15, p = lane >> 4;
    const int src = (h * 16 + q) * IN_F + s * 32 + p * 8;
    *reinterpret_cast<uint4*>(xfrag + (size_t)t * 8) = lda8(x, src, mode);
  } else {
    const int u = t - 16384;                   // u = g*OUT_F + o (writes coalesced)
    if (u < NGRP * OUT_F) {
      const int g = u / OUT_F, o = u - g * OUT_F;
      const float sfv = ld_sz(scales, o * NGRP + g, mode);
      const float zfv = ld_sz(zeros, o * NGRP + g, mode);
      szT[u] = make_float2(sfv, zfv - 128.0f * sfv);
    }
  }
}

// Shared-A LDS dequant-GEMM, round-11: compiler-proof hot loop.
// Round-10 lesson (+10% only): suspected compiler-inserted conservative
// vmcnt waits ordering pending gl_lds B-fills vs C++ ds_reads of smemB
// (same object, runtime offset -> alias-unprovable). Fix: ALL hot-loop LDS
// reads are inline-asm ds_read_b128 (opaque to the compiler's hazard
// tracking); completion enforced by MY lgkmcnt(0) tied to the result regs
// ("+v", rule #18) + sched_barrier(0). Scale/za loads are fully drained
// (vmcnt(0)) in the prologue so no VMEM deps leak into the loop.
// vmcnt ledger (per wave): after barrier outstanding = B0..B3; step s waits
// vmcnt(3) (tail 3,2,1,0); B-fill for s+4 issued right after step s.
// MFMA 16x16x32 bf16; C/D col=lane&15, row=(lane>>4)*4+reg [m89-verified].
__global__ __launch_bounds__(256, 3) void qv_gemm(
    const u16* __restrict__ xfrag, const int* __restrict__ packed,
    const float2* __restrict__ szT, float* __restrict__ part) {
  __shared__ __align__(16) char smemA[32768];        // [s*2+h][1024]
  __shared__ __align__(16) char smemB[4][4][1024];   // [wave][slot][panel]
  const int tid = (int)threadIdx.x;
  const int lane = tid & 63, wid = tid >> 6;
  const int q = lane & 15, p = lane >> 4;
  const int o0 = (int)blockIdx.x * 64 + wid * 16;
  const int ksl = (int)blockIdx.y;               // [0, 8)
  const int o = o0 + q;
  const int k32_0 = ksl * 16;

  // --- S: 4 float2 scale/za loads, fully drained before anything else ---
  const int g0 = ksl * 4;
  float sf[4], za[4];
#pragma unroll
  for (int g = 0; g < 4; ++g) {
    const float2 v = szT[(size_t)(g0 + g) * OUT_F + o];
    sf[g] = v.x; za[g] = v.y;
  }
  asm volatile("s_waitcnt vmcnt(0)" ::: "memory");

  // --- A-stage: 8 gl_lds/wave; wave w covers s_loc = w*4 .. w*4+3 ---
#pragma unroll
  for (int j = 0; j < 4; ++j) {
#pragma unroll
    for (int h = 0; h < 2; ++h) {
      const int s_loc = wid * 4 + j;
      const int sg = k32_0 + s_loc;
      gl_lds16(xfrag + ((size_t)(sg * 2 + h) * 64 + lane) * 8,
               &smemA[(s_loc * 2 + h) * 1024]);
    }
  }
  asm volatile("" ::: "memory");

  // --- B prologue: 4 wave-private gl_lds ---
  const int br = lane >> 2, bc = lane & 3;
  const int* bsrc = packed + (size_t)(o0 + br) * CCOLS + k32_0 * 16
                    + ((bc ^ ((br >> 1) & 3)) << 2);
#pragma unroll
  for (int s = 0; s < 4; ++s) {
    gl_lds16(bsrc + s * 16, &smemB[wid][s][0]);
    asm volatile("" ::: "memory");
  }

  // prologue sync: own A-stage done (4 B outstanding), then raw barrier
  asm volatile("s_waitcnt vmcnt(4)" ::: "memory");
  __builtin_amdgcn_s_barrier();
  __builtin_amdgcn_sched_barrier(0);

  f32x4 acc0 = {0.f, 0.f, 0.f, 0.f}, acc1 = {0.f, 0.f, 0.f, 0.f};
  const int rdoff = q * 64 + ((p ^ ((q >> 1) & 3)) << 4);
  const u32 abase = lds_u32(&smemA[0]) + (u32)(lane * 16);
  const u32 bbase = lds_u32(&smemB[wid][0][0]) + (u32)rdoff;

  // QC: wait B_s -> asm ds_read x3 -> lgkmcnt(0) tied to results -> compute
#define QC(W, SFI, BO, AO0, AO1)                                              \
  {                                                                           \
    asm volatile("s_waitcnt vmcnt(" #W ")" ::: "memory");                     \
    u32x4 bv, a0v, a1v;                                                       \
    asm volatile("ds_read_b128 %0, %1 offset:" BO : "=v"(bv) : "v"(bbase));   \
    asm volatile("ds_read_b128 %0, %1 offset:" AO0 : "=v"(a0v) : "v"(abase)); \
    asm volatile("ds_read_b128 %0, %1 offset:" AO1 : "=v"(a1v) : "v"(abase)); \
    asm volatile("s_waitcnt lgkmcnt(0)"                                       \
                 : "+v"(bv), "+v"(a0v), "+v"(a1v)::"memory");                 \
    __builtin_amdgcn_sched_barrier(0);                                        \
    const u32x4 bw = deq4v(bv, sf[SFI], za[SFI]);                             \
    acc0 = __builtin_amdgcn_mfma_f32_16x16x32_bf16(                           \
        __builtin_bit_cast(short8, a0v), __builtin_bit_cast(short8, bw),      \
        acc0, 0, 0, 0);                                                       \
    acc1 = __builtin_amdgcn_mfma_f32_16x16x32_bf16(                           \
        __builtin_bit_cast(short8, a1v), __builtin_bit_cast(short8, bw),      \
        acc1, 0, 0, 0);                                                       \
    asm volatile("" ::: "memory");                                            \
  }
#define QF(T)                                                                 \
  {                                                                           \
    gl_lds16(bsrc + (T)*16, &smemB[wid][(T) & 3][0]);                         \
    asm volatile("" ::: "memory");                                            \
  }

  QC(3, 0, "0", "0", "1024")           QF(4)
  QC(3, 0, "1024", "2048", "3072")     QF(5)
  QC(3, 0, "2048", "4096", "5120")     QF(6)
  QC(3, 0, "3072", "6144", "7168")     QF(7)
  QC(3, 1, "0", "8192", "9216")        QF(8)
  QC(3, 1, "1024", "10240", "11264")   QF(9)
  QC(3, 1, "2048", "12288", "13312")   QF(10)
  QC(3, 1, "3072", "14336", "15360")   QF(11)
  QC(3, 2, "0", "16384", "17408")      QF(12)
  QC(3, 2, "1024", "18432", "19456")   QF(13)
  QC(3, 2, "2048", "20480", "21504")   QF(14)
  QC(3, 2, "3072", "22528", "23552")   QF(15)
  QC(3, 3, "0", "24576", "25600")
  QC(2, 3, "1024", "26624", "27648")
  QC(1, 3, "2048", "28672", "29696")
  QC(0, 3, "3072", "30720", "31744")
#undef QC
#undef QF

  // lane-contiguous partial store: one 2 KB block per wave
  float* base = part + ((size_t)(ksl * NBX + (int)blockIdx.x) * 4 + wid) * 512
                + lane * 8;
  *reinterpret_cast<f32x4*>(base) = acc0;
  *reinterpret_cast<f32x4*>(base + 4) = acc1;
}

// Reduce over KSPL slices (same partial layout as qv_gemm stores).
__global__ __launch_bounds__(256) void qr_reduce(
    const float* __restrict__ part, const void* __restrict__ scales,
    const void* __restrict__ bias, void* __restrict__ out) {
  const u32 mode = detect_mode((const u16*)scales);
  const int bx = (int)blockIdx.x;           // [0, NBX)
  const int wid = (int)threadIdx.x >> 6, lane = (int)threadIdx.x & 63;
  const int q = lane & 15, p = lane >> 4;
  const int o = bx * 64 + wid * 16 + q;

  float s0[4] = {0.f, 0.f, 0.f, 0.f}, s1[4] = {0.f, 0.f, 0.f, 0.f};
#pragma unroll
  for (int ksl = 0; ksl < KSPL; ++ksl) {
    const float* base = part + ((size_t)(ksl * NBX + bx) * 4 + wid) * 512 + lane * 8;
    const float4 v0 = *reinterpret_cast<const float4*>(base);
    const float4 v1 = *reinterpret_cast<const float4*>(base + 4);
    s0[0] += v0.x; s0[1] += v0.y; s0[2] += v0.z; s0[3] += v0.w;
    s1[0] += v1.x; s1[1] += v1.y; s1[2] += v1.z; s1[3] += v1.w;
  }
  const float bb = ld_sz(bias, o, mode);
#pragma unroll
  for (int rr = 0; rr < 4; ++rr) {
    const float v0 = s0[rr] + bb, v1 = s1[rr] + bb;
    const size_t i0 = (size_t)(p * 4 + rr) * OUT_F + o;
    const size_t i1 = (size_t)(16 + p * 4 + rr) * OUT_F + o;
    if (mode == 1) {
      ((float*)out)[i0] = v0; ((float*)out)[i1] = v1;
    } else {
      ((u16*)out)[i0] = (u16)f2bf_rne(v0);
      ((u16*)out)[i1] = (u16)f2bf_rne(v1);
    }
  }
}

// fallback for tiny ws: round-7 direct kernel (proven correct, slow)
__global__ __launch_bounds__(256, 4) void qp_direct(
    const void* __restrict__ xsrc, const int* __restrict__ packed,
    const void* __restrict__ scales, const void* __restrict__ zeros,
    const void* __restrict__ bias, void* __restrict__ out) {
  constexpr int NSTEP = 128;
  constexpr int BD = 8, AD = 4;
  const u32 mode = detect_mode((const u16*)scales);
  const int tid = (int)threadIdx.x;
  const int lane = tid & 63, wid = tid >> 6;
  const int q = lane & 15, p = lane >> 4;
  const int tile = (int)blockIdx.x * 4 + wid;
  const int o = tile * 16 + q;
  const int* pr = packed + (size_t)o * CCOLS + p * 4;
  const int ae0 = q * IN_F + p * 8;
  const int ae1 = ae0 + 16 * IN_F;
  uint4 bb[BD], a0[AD], a1[AD];
#pragma unroll
  for (int i = 0; i < BD; ++i) bb[i] = *reinterpret_cast<const uint4*>(pr + i * 16);
#pragma unroll
  for (int i = 0; i < AD; ++i) {
    a0[i] = lda8(xsrc, ae0 + i * 32, mode);
    a1[i] = lda8(xsrc, ae1 + i * 32, mode);
  }
  f32x4 acc0 = {0.f, 0.f, 0.f, 0.f}, acc1 = {0.f, 0.f, 0.f, 0.f};
  for (int g = 0; g < NSTEP / 4; ++g) {
    const float sf = ld_sz(scales, o * NGRP + g, mode);
    const float za = ld_sz(zeros, o * NGRP + g, mode) - 128.0f * sf;
#pragma unroll
    for (int u = 0; u < 4; ++u) {
      const int s = g * 4 + u;
      const uint4 bw = deq4(bb[s % BD], sf, za);
      const uint4 av0 = a0[s % AD], av1 = a1[s % AD];
      if (s + BD < NSTEP) bb[s % BD] = *reinterpret_cast<const uint4*>(pr + (s + BD) * 16);
      if (s + AD < NSTEP) {
        a0[s % AD] = lda8(xsrc, ae0 + (s + AD) * 32, mode);
        a1[s % AD] = lda8(xsrc, ae1 + (s + AD) * 32, mode);
      }
      acc0 = __builtin_amdgcn_mfma_f32_16x16x32_bf16(
          __builtin_bit_cast(short8, av0), __builtin_bit_cast(short8, bw), acc0, 0, 0, 0);
      acc1 = __builtin_amdgcn_mfma_f32_16x16x32_bf16(
          __builtin_bit_cast(short8, av1), __builtin_bit_cast(short8, bw), acc1, 0, 0, 0);
    }
  }
  const float bbv = ld_sz(bias, o, mode);
#pragma unroll
  for (int r = 0; r < 4; ++r) {
    const float v0 = acc0[r] + bbv, v1 = acc1[r] + bbv;
    const size_t i0 = (size_t)(p * 4 + r) * OUT_F + o;
    const size_t i1 = (size_t)(16 + p * 4 + r) * OUT_F + o;
    if (mode == 1) { ((float*)out)[i0] = v0; ((float*)out)[i1] = v1; }
    else { ((u16*)out)[i0] = (u16)f2bf_rne(v0); ((u16*)out)[i1] = (u16)f2bf_rne(v1); }
  }
}

extern "C" void kernel_launch(void* const* d_in, const int* in_sizes, int n_in,
                              void* d_out, int out_size, void* d_ws, size_t ws_size,
                              hipStream_t stream) {
  (void)in_sizes; (void)n_in; (void)out_size;
  const void* x      = d_in[0];
  const int* packed  = (const int*)d_in[1];
  const void* scales = d_in[2];
  const void* zeros  = d_in[3];
  const void* bias   = d_in[4];

  if (ws_size >= WS_NEED) {
    u16* xfrag = (u16*)d_ws;
    float2* szT = (float2*)((char*)d_ws + SZ_OFF);
    float* part = (float*)((char*)d_ws + PART_OFF);
    qz_prep<<<1440, 256, 0, stream>>>(x, scales, zeros, xfrag, szT);
    qv_gemm<<<dim3(NBX, KSPL), 256, 0, stream>>>(xfrag, packed, szT, part);
    qr_reduce<<<NBX, 256, 0, stream>>>(part, scales, bias, d_out);
  } else {
    qp_direct<<<OUT_F / 64, 256, 0, stream>>>(x, packed, scales, zeros, bias, d_out);
  }
}